// Round 6
// baseline (681.175 us; speedup 1.0000x reference)
//
#include <hip/hip_runtime.h>
#include <hip/hip_cooperative_groups.h>
#include <math.h>

// GCN: h1 = relu(norm_dst * A * (norm_src * x) @ W1 + b1)
//      h2 = relu(norm_dst * A * (norm_src * h1) @ W2 + b2)
//      hg = mean_per_graph(h2); out = relu(hg@Wr1+br1)@Wr2+br2
// d_out = [out (64*128) | h2 (N*128)]
//
// R2-R9: CSR-by-dst + register gather; two-level counting sort; fp16 MFMA
//        pipeline. Gather pinned at ~60us random-read floor (3.9 TB/s).
// R10/R11: FAILED - deg via random global atomics (+48us memory-side RMW).
// R12: bucket 512->256 neutral. R13: merged build (coarse+cscatter), padded
//        buckets, no scan: 411->383. Top-5 all gather2 => every other kernel
//        <60us; ~150us unattributed => inter-dispatch gaps (~10us x 9).
// R15: cooperative fusion. k_graph = prep+build+fine+gemm1 (1 dispatch,
//        grid.sync between phases; 1024 blocks x 256 thr, 4 blocks/CU
//        co-resident, LDS union 38.9KB). k_tail = pool+readout. 9->5
//        dispatches. Hot kernels (gather1/gemm2/gather2) untouched.
// Assumes N <= 131072 (src fits 17 bits in packing).

#define D 128
#define BSH 8
#define BKT 256      // nodes per bucket
#define CAP 4608     // padded bucket capacity (avg 4096, sigma 64 -> +8 sigma)

typedef _Float16 half8 __attribute__((ext_vector_type(8)));
typedef _Float16 half4v __attribute__((ext_vector_type(4)));
typedef _Float16 half2v __attribute__((ext_vector_type(2)));
typedef float f32x4 __attribute__((ext_vector_type(4)));

union H8 { half8 v; half2v h[4]; };

union BigLds {
  struct { int hd[512], hs[512], based[512], bases[512]; } b;            // 8KB
  struct { int hist[256], excl[256], ecache[CAP], sorted[CAP]; } f;      // 38.9KB
  struct { int hist[256]; } fs;                                          // 1KB
  struct { _Float16 As[64][136]; _Float16 Cs[64][128]; } g;              // 33.8KB
};

// ================= cooperative graph kernel: prep+build+fine+gemm1 ==========
__global__ __launch_bounds__(256, 4) void k_graph(
    const float* __restrict__ W1, const float* __restrict__ W2,
    _Float16* __restrict__ Wt1, _Float16* __restrict__ Wt2,
    int* __restrict__ cnt_d, int* __restrict__ cnt_s,
    float* __restrict__ pool, const int* __restrict__ gid,
    int* __restrict__ gptr,
    const int* __restrict__ src, const int* __restrict__ dst,
    int* __restrict__ packed_d, int* __restrict__ packed_s,
    int* __restrict__ row_lo, int* __restrict__ row_hi,
    int* __restrict__ csr, float* __restrict__ norm_src,
    const float* __restrict__ x, _Float16* __restrict__ P,
    int N, int E, int nbkt) {
  __shared__ BigLds sh;
  cooperative_groups::grid_group grid = cooperative_groups::this_grid();
  const int t = threadIdx.x;
  const int bid = blockIdx.x;
  const int G = gridDim.x;

  // ---------- P0: prep (Wt transpose, zero cnt/pool, gptr bsearch) ----------
  for (int idx = bid * 256 + t; idx < 2 * 128 * 128; idx += G * 256) {
    int m = idx >> 14, i = idx & 16383;
    int k = i >> 7, n = i & 127;
    (m ? Wt2 : Wt1)[n * 128 + k] = (_Float16)((m ? W2 : W1)[i]);
  }
  if (bid == 0) {
    for (int i = t; i < 1024; i += 256) cnt_d[i] = 0;  // cnt_d[512]+cnt_s[512]
    for (int i = t; i < 64 * D; i += 256) pool[i] = 0.0f;
    if (t <= 64) {  // gptr[g] = lower_bound(gid, g)
      int lo = 0, hi = N;
      while (lo < hi) {
        int m = (lo + hi) >> 1;
        if (gid[m] < t) lo = m + 1; else hi = m;
      }
      gptr[t] = lo;
    }
  }
  grid.sync();

  // ---------- P1: build (histogram + slot reservation + scatter) ----------
  {
    sh.b.hd[t] = 0; sh.b.hd[t + 256] = 0;
    sh.b.hs[t] = 0; sh.b.hs[t + 256] = 0;
    __syncthreads();
    int chunk = (E + G - 1) / G;
    int lo = bid * chunk, hi = min(lo + chunk, E);
    for (int i = lo + t; i < hi; i += 256) {
      atomicAdd(&sh.b.hd[dst[i] >> BSH], 1);
      atomicAdd(&sh.b.hs[src[i] >> BSH], 1);
    }
    __syncthreads();
    int c0d = sh.b.hd[t], c1d = sh.b.hd[t + 256];
    int c0s = sh.b.hs[t], c1s = sh.b.hs[t + 256];
    __syncthreads();
    sh.b.hd[t] = 0; sh.b.hd[t + 256] = 0;   // reuse as rank counters
    sh.b.hs[t] = 0; sh.b.hs[t + 256] = 0;
    if (t < nbkt)       sh.b.based[t]       = c0d ? atomicAdd(&cnt_d[t], c0d) : 0;
    if (t + 256 < nbkt) sh.b.based[t + 256] = c1d ? atomicAdd(&cnt_d[t + 256], c1d) : 0;
    if (t < nbkt)       sh.b.bases[t]       = c0s ? atomicAdd(&cnt_s[t], c0s) : 0;
    if (t + 256 < nbkt) sh.b.bases[t + 256] = c1s ? atomicAdd(&cnt_s[t + 256], c1s) : 0;
    __syncthreads();
    for (int i = lo + t; i < hi; i += 256) {   // re-read chunk (L1/L2 hot)
      int s = src[i], d = dst[i];
      int b1 = d >> BSH;
      int p1 = sh.b.based[b1] + atomicAdd(&sh.b.hd[b1], 1);
      if (p1 < CAP) packed_d[b1 * CAP + p1] = ((d & (BKT - 1)) << 17) | s;
      int b2 = s >> BSH;
      int p2 = sh.b.bases[b2] + atomicAdd(&sh.b.hs[b2], 1);
      if (p2 < CAP) packed_s[b2 * CAP + p2] = s & (BKT - 1);
    }
  }
  grid.sync();

  // ---------- P2: fine (per-bucket counting sort + norm_src) ----------
  for (int task = bid; task < 2 * nbkt; task += G) {
    if (task >= nbkt) {
      // src side: norm_src = rsqrt(max(deg_out,1))
      int b = task - nbkt;
      int lo = b * CAP;
      int cnt = min(cnt_s[b], CAP);
      sh.fs.hist[t] = 0;
      __syncthreads();
      for (int e = t; e < cnt; e += 256)
        atomicAdd(&sh.fs.hist[packed_s[lo + e]], 1);
      __syncthreads();
      int nbase = b << BSH;
      if (nbase + t < N)
        norm_src[nbase + t] = rsqrtf(fmaxf((float)sh.fs.hist[t], 1.0f));
      __syncthreads();
    } else {
      // dst side: row_lo/row_hi + csr (coalesced write via LDS sort)
      int b = task;
      int lo = b * CAP;
      int cnt = min(cnt_d[b], CAP);
      sh.f.hist[t] = 0;
      __syncthreads();
      for (int e = t; e < cnt; e += 256) {
        int p = packed_d[lo + e];
        sh.f.ecache[e] = p;
        atomicAdd(&sh.f.hist[p >> 17], 1);
      }
      __syncthreads();
      int v = sh.f.hist[t];
      for (int off = 1; off < 256; off <<= 1) {
        int a = (t >= off) ? sh.f.hist[t - off] : 0;
        __syncthreads();
        sh.f.hist[t] += a;
        __syncthreads();
      }
      sh.f.excl[t] = sh.f.hist[t] - v;
      int nbase = b << BSH;
      if (nbase + t < N) {
        row_lo[nbase + t] = lo + sh.f.hist[t] - v;
        row_hi[nbase + t] = lo + sh.f.hist[t];
      }
      __syncthreads();
      sh.f.hist[t] = 0;  // reuse as rank counters
      __syncthreads();
      for (int e = t; e < cnt; e += 256) {
        int p = sh.f.ecache[e];
        int dlow = p >> 17;
        int r = atomicAdd(&sh.f.hist[dlow], 1);
        sh.f.sorted[sh.f.excl[dlow] + r] = p & 0x1FFFF;
      }
      __syncthreads();
      for (int e = t; e < cnt; e += 256)   // coalesced csr write
        csr[lo + e] = sh.f.sorted[e];
      __syncthreads();
    }
  }
  grid.sync();

  // ---------- P3: gemm1  P(half) = (norm_src*x)@W1 ----------
  {
    const int ntiles = (N + 63) >> 6;
    const int w = t >> 6, l = t & 63;
    const int c = l & 15, quad = l >> 4;
    for (int tile = bid; tile < ntiles; tile += G) {
      const int r0 = tile * 64;
      for (int i = t; i < 64 * 32; i += 256) {
        int r = i >> 5, c4 = i & 31;
        float4 v = {0.f, 0.f, 0.f, 0.f};
        if (r0 + r < N) {
          v = ((const float4*)x)[(size_t)(r0 + r) * 32 + c4];
          float s = norm_src[r0 + r];
          v.x *= s; v.y *= s; v.z *= s; v.w *= s;
        }
        half4v h = {(_Float16)v.x, (_Float16)v.y, (_Float16)v.z, (_Float16)v.w};
        *(half4v*)&sh.g.As[r][c4 * 4] = h;
      }
      __syncthreads();
      f32x4 acc[8];
#pragma unroll
      for (int nt = 0; nt < 8; ++nt) acc[nt] = (f32x4){0.f, 0.f, 0.f, 0.f};
#pragma unroll
      for (int kc = 0; kc < 4; ++kc) {
        half8 a = *(const half8*)&sh.g.As[w * 16 + c][kc * 32 + quad * 8];
#pragma unroll
        for (int nt = 0; nt < 8; ++nt) {
          half8 b = *(const half8*)&Wt1[(size_t)(nt * 16 + c) * 128 + kc * 32 + quad * 8];
          acc[nt] = __builtin_amdgcn_mfma_f32_16x16x32_f16(a, b, acc[nt], 0, 0, 0);
        }
      }
#pragma unroll
      for (int nt = 0; nt < 8; ++nt)
#pragma unroll
        for (int r = 0; r < 4; ++r)
          sh.g.Cs[w * 16 + quad * 4 + r][nt * 16 + c] = (_Float16)acc[nt][r];
      __syncthreads();
      for (int i = t; i < 64 * 16; i += 256) {
        int r = i >> 4, c8 = i & 15;
        if (r0 + r < N)
          ((half8*)P)[(size_t)(r0 + r) * 16 + c8] = *(half8*)&sh.g.Cs[r][c8 * 8];
      }
      __syncthreads();
    }
  }
}

// ================= cooperative tail kernel: pool + readout ==================
__global__ __launch_bounds__(256, 2) void k_tail(
    const float* __restrict__ H, const int* __restrict__ gptr,
    float* __restrict__ pool,
    const float* __restrict__ Wr1, const float* __restrict__ br1,
    const float* __restrict__ Wr2, const float* __restrict__ br2,
    float* __restrict__ out) {
  cooperative_groups::grid_group grid = cooperative_groups::this_grid();
  const int t = threadIdx.x;
  const int bid = blockIdx.x;
  const int G = gridDim.x;
  __shared__ float red[256];
  __shared__ float hg[128];
  __shared__ float t1[128];

  for (int task = bid; task < 512; task += G) {
    int g = task >> 3, chunk = task & 7;
    int col = t & 127, rpar = t >> 7;
    int s = gptr[g], e = gptr[g + 1];
    float acc = 0.0f;
    for (int r = s + chunk * 2 + rpar; r < e; r += 16)
      acc += H[(size_t)r * D + col];
    red[t] = acc;
    __syncthreads();
    if (rpar == 0) atomicAdd(&pool[g * D + col], acc + red[t + 128]);
    __syncthreads();
  }
  grid.sync();
  for (int g = bid; g < 64; g += G) {
    float cnt = fmaxf((float)(gptr[g + 1] - gptr[g]), 1.0f);
    if (t < 128) hg[t] = pool[(size_t)g * D + t] / cnt;
    __syncthreads();
    if (t < 128) {
      float a = br1[t];
      for (int k = 0; k < D; ++k) a += hg[k] * Wr1[(size_t)k * D + t];
      t1[t] = fmaxf(a, 0.0f);
    }
    __syncthreads();
    if (t < 128) {
      float b = br2[t];
      for (int k = 0; k < D; ++k) b += t1[k] * Wr2[(size_t)k * D + t];
      out[(size_t)g * D + t] = b;
    }
    __syncthreads();
  }
}

// ---------------- MFMA GEMM (fp16 pre-scaled input): C(half) = A@W -----------
__global__ __launch_bounds__(256) void k_gemm2(const _Float16* __restrict__ A,
                                               const _Float16* __restrict__ Wt,
                                               _Float16* __restrict__ C, int N) {
  __shared__ _Float16 As[64][136];
  __shared__ _Float16 Cs[64][128];
  const int r0 = blockIdx.x * 64;
  const int t = threadIdx.x;
  for (int i = t; i < 64 * 16; i += 256) {
    int r = i >> 4, c8 = i & 15;
    half8 v = {0, 0, 0, 0, 0, 0, 0, 0};
    if (r0 + r < N) v = ((const half8*)A)[(size_t)(r0 + r) * 16 + c8];
    *(half8*)&As[r][c8 * 8] = v;
  }
  __syncthreads();
  const int w = t >> 6, l = t & 63;
  const int c = l & 15, quad = l >> 4;
  f32x4 acc[8];
#pragma unroll
  for (int nt = 0; nt < 8; ++nt) acc[nt] = (f32x4){0.f, 0.f, 0.f, 0.f};
#pragma unroll
  for (int kc = 0; kc < 4; ++kc) {
    half8 a = *(const half8*)&As[w * 16 + c][kc * 32 + quad * 8];
#pragma unroll
    for (int nt = 0; nt < 8; ++nt) {
      half8 b = *(const half8*)&Wt[(size_t)(nt * 16 + c) * 128 + kc * 32 + quad * 8];
      acc[nt] = __builtin_amdgcn_mfma_f32_16x16x32_f16(a, b, acc[nt], 0, 0, 0);
    }
  }
#pragma unroll
  for (int nt = 0; nt < 8; ++nt)
#pragma unroll
    for (int r = 0; r < 4; ++r)
      Cs[w * 16 + quad * 4 + r][nt * 16 + c] = (_Float16)acc[nt][r];
  __syncthreads();
  for (int i = t; i < 64 * 16; i += 256) {
    int r = i >> 4, c8 = i & 15;
    if (r0 + r < N)
      ((half8*)C)[(size_t)(r0 + r) * 16 + c8] = *(half8*)&Cs[r][c8 * 8];
  }
}

// ---------------- gather core ----------------
#define PK_ROW(u)                                                           \
  _Pragma("unroll")                                                         \
  for (int k = 0; k < 4; ++k) acch[k] += (u).h[k];

__device__ __forceinline__ void gather_core(const half8* __restrict__ P8,
                                            const int* __restrict__ csr,
                                            int start, int end, int cg, int eg,
                                            int lane, float* acc) {
  half2v acch[4] = {{(_Float16)0.f, (_Float16)0.f}, {(_Float16)0.f, (_Float16)0.f},
                    {(_Float16)0.f, (_Float16)0.f}, {(_Float16)0.f, (_Float16)0.f}};
  for (int s0 = start; s0 < end; s0 += 64) {
    int cnt = min(64, end - s0);
    int idx = (s0 + lane < end) ? csr[s0 + lane] : 0;
    int base = 0;
    for (; base + 16 <= cnt; base += 16) {
      int i0 = __shfl(idx, base + eg);
      int i1 = __shfl(idx, base + 4 + eg);
      int i2 = __shfl(idx, base + 8 + eg);
      int i3 = __shfl(idx, base + 12 + eg);
      H8 u0, u1, u2, u3;
      u0.v = P8[(size_t)i0 * 16 + cg];
      u1.v = P8[(size_t)i1 * 16 + cg];
      u2.v = P8[(size_t)i2 * 16 + cg];
      u3.v = P8[(size_t)i3 * 16 + cg];
      PK_ROW(u0) PK_ROW(u1) PK_ROW(u2) PK_ROW(u3)
    }
    for (; base + 4 <= cnt; base += 4) {
      int i0 = __shfl(idx, base + eg);
      H8 u0;
      u0.v = P8[(size_t)i0 * 16 + cg];
      PK_ROW(u0)
    }
    if (base < cnt) {  // 1-3 tail edges
      int j = min(base + eg, cnt - 1);
      int i0 = __shfl(idx, j);
      if (base + eg < cnt) {
        H8 u0;
        u0.v = P8[(size_t)i0 * 16 + cg];
        PK_ROW(u0)
      }
    }
  }
#pragma unroll
  for (int k = 0; k < 4; ++k) {
    acc[2 * k]     = (float)acch[k].x;
    acc[2 * k + 1] = (float)acch[k].y;
  }
#pragma unroll
  for (int j = 0; j < 8; ++j) {
    acc[j] += __shfl_xor(acc[j], 16);
    acc[j] += __shfl_xor(acc[j], 32);
  }
}

// gather 1: h1' = norm_src * relu(agg*nd + b), fp16 out
__global__ __launch_bounds__(256) void k_gather1(const half8* __restrict__ P8,
                                                 const int* __restrict__ row_lo,
                                                 const int* __restrict__ row_hi,
                                                 const int* __restrict__ csr,
                                                 const float* __restrict__ bias,
                                                 const float* __restrict__ norm_src,
                                                 half2v* __restrict__ outH, int N) {
  int wid = (blockIdx.x * 256 + threadIdx.x) >> 6;
  if (wid >= N) return;
  int lane = threadIdx.x & 63;
  int cg = lane & 15, eg = lane >> 4;
  int start = row_lo[wid], end = row_hi[wid];
  float acc[8];
  gather_core(P8, csr, start, end, cg, eg, lane, acc);
  float nd = rsqrtf(fmaxf((float)(end - start), 1.0f));
  float ns = norm_src[wid];
  float2 b = ((const float2*)bias)[cg * 4 + eg];
  half2v o = {(_Float16)(fmaxf(acc[eg * 2] * nd + b.x, 0.f) * ns),
              (_Float16)(fmaxf(acc[eg * 2 + 1] * nd + b.y, 0.f) * ns)};
  outH[(size_t)wid * 64 + cg * 4 + eg] = o;
}

// gather 2: h2 = relu(agg*nd + b), fp32 out
__global__ __launch_bounds__(256) void k_gather2(const half8* __restrict__ P8,
                                                 const int* __restrict__ row_lo,
                                                 const int* __restrict__ row_hi,
                                                 const int* __restrict__ csr,
                                                 const float* __restrict__ bias,
                                                 float2* __restrict__ outH, int N) {
  int wid = (blockIdx.x * 256 + threadIdx.x) >> 6;
  if (wid >= N) return;
  int lane = threadIdx.x & 63;
  int cg = lane & 15, eg = lane >> 4;
  int start = row_lo[wid], end = row_hi[wid];
  float acc[8];
  gather_core(P8, csr, start, end, cg, eg, lane, acc);
  float nd = rsqrtf(fmaxf((float)(end - start), 1.0f));
  float2 b = ((const float2*)bias)[cg * 4 + eg];
  float2 o;
  o.x = fmaxf(acc[eg * 2] * nd + b.x, 0.f);
  o.y = fmaxf(acc[eg * 2 + 1] * nd + b.y, 0.f);
  outH[(size_t)wid * 64 + cg * 4 + eg] = o;
}

extern "C" void kernel_launch(void* const* d_in, const int* in_sizes, int n_in,
                              void* d_out, int out_size, void* d_ws, size_t ws_size,
                              hipStream_t stream) {
  const float* x   = (const float*)d_in[0];
  const int* edge  = (const int*)d_in[1];
  const int* gid   = (const int*)d_in[2];
  const float* W1  = (const float*)d_in[4];
  const float* b1  = (const float*)d_in[5];
  const float* W2  = (const float*)d_in[6];
  const float* b2  = (const float*)d_in[7];
  const float* Wr1 = (const float*)d_in[8];
  const float* br1 = (const float*)d_in[9];
  const float* Wr2 = (const float*)d_in[10];
  const float* br2 = (const float*)d_in[11];

  const int N = in_sizes[0] / D;   // 100000
  const int E = in_sizes[1] / 2;   // 1600000
  const int* src = edge;
  const int* dst = edge + E;
  const int nbkt = (N + BKT - 1) >> BSH;  // 391

  // workspace layout
  float* bufA     = (float*)d_ws;                    // P (half N*128) lives here
  float* bufB     = bufA + (size_t)N * D;            // h1' (half N*128) lives here
  int* row_lo     = (int*)(bufB + (size_t)N * D);    // N
  int* row_hi     = row_lo + N;                      // N
  int* csr        = row_hi + N;                      // nbkt*CAP (bucket-padded)
  float* norm_src = (float*)(csr + (size_t)nbkt * CAP);  // N
  float* pool     = norm_src + N;                    // 64*128
  int* gptr       = (int*)(pool + 64 * D);           // 65
  int* cnt_d      = gptr + 65;                       // 512
  int* cnt_s      = cnt_d + 512;                     // 512 (adjacent)
  _Float16* Wt1   = (_Float16*)(cnt_s + 512);        // 128*128 halves
  _Float16* Wt2   = Wt1 + 128 * 128;                 // 128*128 halves
  // temporaries aliasing bufA (consumed in k_graph P2 before P3 writes P)
  int* packed_d   = (int*)bufA;                      // nbkt*CAP
  int* packed_s   = packed_d + (size_t)nbkt * CAP;   // nbkt*CAP
  size_t need = ((size_t)2 * N * D + 3 * (size_t)N + (size_t)nbkt * CAP
                 + 64 * D + 65 + 1024 + 16384 + 1024) * sizeof(float);
  if (ws_size < need) return;

  float* out_g = (float*)d_out;      // 64*128
  float* h_out = out_g + 64 * D;     // N*128

  _Float16* P   = (_Float16*)bufA;
  _Float16* h1p = (_Float16*)bufB;

  // cached cooperative grid sizes (co-residency-safe)
  static int G1 = 0, G2 = 0;
  if (G1 == 0) {
    int occ1 = 0, occ2 = 0, ncu = 256;
    hipOccupancyMaxActiveBlocksPerMultiprocessor(&occ1, k_graph, 256, 0);
    hipOccupancyMaxActiveBlocksPerMultiprocessor(&occ2, k_tail, 256, 0);
    hipDeviceProp_t prop;
    int dev = 0;
    if (hipGetDevice(&dev) == hipSuccess &&
        hipGetDeviceProperties(&prop, dev) == hipSuccess &&
        prop.multiProcessorCount > 0)
      ncu = prop.multiProcessorCount;
    G1 = (occ1 > 0) ? min(1024, occ1 * ncu) : 1024;
    G2 = (occ2 > 0) ? min(512, occ2 * ncu) : 512;
  }

  // ---- k_graph: prep + build + fine + gemm1 (cooperative) ----
  {
    int n_ = N, e_ = E, nb_ = nbkt;
    void* args[] = {
      (void*)&W1, (void*)&W2, (void*)&Wt1, (void*)&Wt2,
      (void*)&cnt_d, (void*)&cnt_s, (void*)&pool, (void*)&gid, (void*)&gptr,
      (void*)&src, (void*)&dst, (void*)&packed_d, (void*)&packed_s,
      (void*)&row_lo, (void*)&row_hi, (void*)&csr, (void*)&norm_src,
      (void*)&x, (void*)&P, (void*)&n_, (void*)&e_, (void*)&nb_};
    hipLaunchCooperativeKernel(k_graph, dim3(G1), dim3(256), args, 0, stream);
  }

  // layer 1 gather
  k_gather1<<<(N * 64 + 255) / 256, 256, 0, stream>>>(
      (const half8*)P, row_lo, row_hi, csr, b1, norm_src, (half2v*)h1p, N);

  // layer 2
  const int gemm_grid = (N + 63) / 64;
  k_gemm2<<<gemm_grid, 256, 0, stream>>>(h1p, Wt2, P, N);
  k_gather2<<<(N * 64 + 255) / 256, 256, 0, stream>>>(
      (const half8*)P, row_lo, row_hi, csr, b2, (float2*)h_out, N);

  // ---- k_tail: pool + readout (cooperative) ----
  {
    void* args[] = {
      (void*)&h_out, (void*)&gptr, (void*)&pool,
      (void*)&Wr1, (void*)&br1, (void*)&Wr2, (void*)&br2, (void*)&out_g};
    hipLaunchCooperativeKernel(k_tail, dim3(G2), dim3(256), args, 0, stream);
  }
}

// Round 7
// 463.570 us; speedup vs baseline: 1.4694x; 1.4694x over previous
//
#include <hip/hip_runtime.h>
#include <hip/hip_cooperative_groups.h>
#include <math.h>

// GCN: h1 = relu(norm_dst * A * (norm_src * x) @ W1 + b1)
//      h2 = relu(norm_dst * A * (norm_src * h1) @ W2 + b2)
//      hg = mean_per_graph(h2); out = relu(hg@Wr1+br1)@Wr2+br2
// d_out = [out (64*128) | h2 (N*128)]
//
// R2-R9: CSR-by-dst + register gather; two-level counting sort; fp16 MFMA
//        pipeline. Gather pinned at ~60us random-read floor (3.9 TB/s).
// R10/R11: FAILED - deg via random global atomics (+48us memory-side RMW).
// R12: bucket 512->256 neutral (411). R13: merged build + padded buckets +
//        LDS-sorted coalesced csr: 383us.
// R15: FAILED - cooperative k_graph(prep+build+fine+gemm1) @ launch_bounds
//        (256,4) -> 60 VGPRs -> gemm1 acc[8] spilled to scratch (WRITE_SIZE
//        125MB vs 56MB real; VALUBusy 1.2%): 681us. Lesson: never fuse
//        high-VGPR MFMA phases with low-VGPR phases under one launch bound.
// R16: revert to R13 structure; keep only the safe fusion: cooperative k_tail
//        (pool+readout, both trivial-VGPR). 9 -> 8 dispatches.
// Assumes N <= 131072 (src fits 17 bits in packing).

#define D 128
#define BSH 8
#define BKT 256      // nodes per bucket
#define CAP 4608     // padded bucket capacity (avg 4096, sigma 64 -> +8 sigma)
#define SCHUNK 3200  // edges staged per build block

typedef _Float16 half8 __attribute__((ext_vector_type(8)));
typedef _Float16 half4v __attribute__((ext_vector_type(4)));
typedef _Float16 half2v __attribute__((ext_vector_type(2)));
typedef float f32x4 __attribute__((ext_vector_type(4)));

union H8 { half8 v; half2v h[4]; };

// ---------------- merged coarse histogram + scatter (single edge read) --------
__global__ __launch_bounds__(512) void k_build(const int* __restrict__ src,
                                               const int* __restrict__ dst,
                                               int* __restrict__ cnt_d,
                                               int* __restrict__ cnt_s,
                                               int* __restrict__ packed_d,
                                               int* __restrict__ packed_s,
                                               int E, int nbkt) {
  __shared__ int es[SCHUNK], ed[SCHUNK];
  __shared__ int hd[512], hs[512], based[512], bases[512];
  int t = threadIdx.x;
  hd[t] = 0; hs[t] = 0;
  __syncthreads();
  int chunk = (E + gridDim.x - 1) / gridDim.x;  // == SCHUNK
  int lo = blockIdx.x * chunk, hi = min(lo + chunk, E);
  int n = hi - lo;
  for (int i = t; i < n; i += 512) {
    int s = src[lo + i], d = dst[lo + i];
    es[i] = s; ed[i] = d;
    atomicAdd(&hd[d >> BSH], 1);
    atomicAdd(&hs[s >> BSH], 1);
  }
  __syncthreads();
  int cD = (t < nbkt) ? hd[t] : 0;
  int cS = (t < nbkt) ? hs[t] : 0;
  __syncthreads();
  hd[t] = 0; hs[t] = 0;   // reuse as rank counters
  if (t < nbkt) {
    based[t] = cD ? atomicAdd(&cnt_d[t], cD) : 0;
    bases[t] = cS ? atomicAdd(&cnt_s[t], cS) : 0;
  }
  __syncthreads();
  for (int i = t; i < n; i += 512) {
    int s = es[i], d = ed[i];
    int b1 = d >> BSH;
    int p1 = based[b1] + atomicAdd(&hd[b1], 1);
    if (p1 < CAP) packed_d[b1 * CAP + p1] = ((d & (BKT - 1)) << 17) | s;
    int b2 = s >> BSH;
    int p2 = bases[b2] + atomicAdd(&hs[b2], 1);
    if (p2 < CAP) packed_s[b2 * CAP + p2] = s & (BKT - 1);
  }
}

// ---------------- fine pass: blocks [0,nbkt) dst, [nbkt,2*nbkt) src ----------
// dst: per-bucket counting sort fully in LDS; csr written coalesced.
__global__ __launch_bounds__(512) void k_fine(const int* __restrict__ packed_d,
                                              const int* __restrict__ cnt_d,
                                              int* __restrict__ row_lo,
                                              int* __restrict__ row_hi,
                                              int* __restrict__ csr,
                                              const int* __restrict__ packed_s,
                                              const int* __restrict__ cnt_s,
                                              float* __restrict__ norm_src,
                                              int N, int nbkt) {
  __shared__ int hist[256];
  int t = threadIdx.x;
  if (blockIdx.x >= nbkt) {
    // ---- src side: norm_src = rsqrt(max(deg_out,1)) ----
    int b = blockIdx.x - nbkt;
    int lo = b * CAP;
    int cnt = min(cnt_s[b], CAP);
    if (t < 256) hist[t] = 0;
    __syncthreads();
    for (int e = t; e < cnt; e += 512)
      atomicAdd(&hist[packed_s[lo + e]], 1);
    __syncthreads();
    int nbase = b << BSH;
    if (t < 256 && nbase + t < N)
      norm_src[nbase + t] = rsqrtf(fmaxf((float)hist[t], 1.0f));
    return;
  }
  // ---- dst side: row_lo/row_hi + csr ----
  __shared__ int excl[256];
  __shared__ int ecache[CAP];
  __shared__ int sorted[CAP];
  int b = blockIdx.x;
  int lo = b * CAP;
  int cnt = min(cnt_d[b], CAP);
  if (t < 256) hist[t] = 0;
  __syncthreads();
  for (int e = t; e < cnt; e += 512) {
    int p = packed_d[lo + e];
    ecache[e] = p;
    atomicAdd(&hist[p >> 17], 1);
  }
  __syncthreads();
  int v = (t < 256) ? hist[t] : 0;
  // inclusive scan of hist (256 entries; all threads hit barriers)
  for (int off = 1; off < 256; off <<= 1) {
    int a = (t >= off && t < 256) ? hist[t - off] : 0;
    __syncthreads();
    if (t < 256) hist[t] += a;
    __syncthreads();
  }
  int nbase = b << BSH;
  if (t < 256) {
    excl[t] = hist[t] - v;
    if (nbase + t < N) {
      row_lo[nbase + t] = lo + hist[t] - v;
      row_hi[nbase + t] = lo + hist[t];
    }
  }
  __syncthreads();
  if (t < 256) hist[t] = 0;  // reuse as rank counters
  __syncthreads();
  for (int e = t; e < cnt; e += 512) {
    int p = ecache[e];
    int dlow = p >> 17;
    int r = atomicAdd(&hist[dlow], 1);
    sorted[excl[dlow] + r] = p & 0x1FFFF;
  }
  __syncthreads();
  for (int e = t; e < cnt; e += 512)   // coalesced csr write
    csr[lo + e] = sorted[e];
}

// ---------------- prep: Wt transpose + zero cnt/pool + gptr bsearch ----------
__global__ __launch_bounds__(256) void k_prep(const float* __restrict__ W1,
                                              const float* __restrict__ W2,
                                              _Float16* __restrict__ Wt1,
                                              _Float16* __restrict__ Wt2,
                                              int* __restrict__ cnt_d,
                                              float* __restrict__ pool,
                                              const int* __restrict__ gid,
                                              int* __restrict__ gptr, int N) {
  if (blockIdx.x == 128) {
    int t = threadIdx.x;
    cnt_d[t] = 0; cnt_d[t + 256] = 0; cnt_d[t + 512] = 0; cnt_d[t + 768] = 0;
    for (int i = t; i < 64 * D; i += 256) pool[i] = 0.0f;
    if (t <= 64) {  // gptr[g] = lower_bound(gid, g)
      int lo = 0, hi = N;
      while (lo < hi) {
        int m = (lo + hi) >> 1;
        if (gid[m] < t) lo = m + 1; else hi = m;
      }
      gptr[t] = lo;
    }
    return;
  }
  int idx = blockIdx.x * 256 + threadIdx.x;
  int m = idx >> 14;
  int i = idx & 16383;
  int k = i >> 7, n = i & 127;
  const float* W = m ? W2 : W1;
  _Float16* Wt = m ? Wt2 : Wt1;
  Wt[n * 128 + k] = (_Float16)W[i];  // i == k*128+n
}

// ---------------- MFMA GEMM (fp32 input): C(half) = (scale*A)@W ----------------
__global__ __launch_bounds__(256) void k_gemm1(const float* __restrict__ A,
                                               const _Float16* __restrict__ Wt,
                                               const float* __restrict__ scale,
                                               _Float16* __restrict__ C, int N) {
  __shared__ _Float16 As[64][136];
  __shared__ _Float16 Cs[64][128];
  const int r0 = blockIdx.x * 64;
  const int t = threadIdx.x;
  for (int i = t; i < 64 * 32; i += 256) {
    int r = i >> 5, c4 = i & 31;
    float4 v = {0.f, 0.f, 0.f, 0.f};
    if (r0 + r < N) {
      v = ((const float4*)A)[(size_t)(r0 + r) * 32 + c4];
      float s = scale[r0 + r];
      v.x *= s; v.y *= s; v.z *= s; v.w *= s;
    }
    half4v h = {(_Float16)v.x, (_Float16)v.y, (_Float16)v.z, (_Float16)v.w};
    *(half4v*)&As[r][c4 * 4] = h;
  }
  __syncthreads();
  const int w = t >> 6, l = t & 63;
  const int c = l & 15, quad = l >> 4;
  f32x4 acc[8];
#pragma unroll
  for (int nt = 0; nt < 8; ++nt) acc[nt] = (f32x4){0.f, 0.f, 0.f, 0.f};
#pragma unroll
  for (int kc = 0; kc < 4; ++kc) {
    half8 a = *(const half8*)&As[w * 16 + c][kc * 32 + quad * 8];
#pragma unroll
    for (int nt = 0; nt < 8; ++nt) {
      half8 b = *(const half8*)&Wt[(size_t)(nt * 16 + c) * 128 + kc * 32 + quad * 8];
      acc[nt] = __builtin_amdgcn_mfma_f32_16x16x32_f16(a, b, acc[nt], 0, 0, 0);
    }
  }
#pragma unroll
  for (int nt = 0; nt < 8; ++nt)
#pragma unroll
    for (int r = 0; r < 4; ++r)
      Cs[w * 16 + quad * 4 + r][nt * 16 + c] = (_Float16)acc[nt][r];
  __syncthreads();
  for (int i = t; i < 64 * 16; i += 256) {
    int r = i >> 4, c8 = i & 15;
    if (r0 + r < N)
      ((half8*)C)[(size_t)(r0 + r) * 16 + c8] = *(half8*)&Cs[r][c8 * 8];
  }
}

// ---------------- MFMA GEMM (fp16 pre-scaled input): C(half) = A@W -----------
__global__ __launch_bounds__(256) void k_gemm2(const _Float16* __restrict__ A,
                                               const _Float16* __restrict__ Wt,
                                               _Float16* __restrict__ C, int N) {
  __shared__ _Float16 As[64][136];
  __shared__ _Float16 Cs[64][128];
  const int r0 = blockIdx.x * 64;
  const int t = threadIdx.x;
  for (int i = t; i < 64 * 16; i += 256) {
    int r = i >> 4, c8 = i & 15;
    half8 v = {0, 0, 0, 0, 0, 0, 0, 0};
    if (r0 + r < N) v = ((const half8*)A)[(size_t)(r0 + r) * 16 + c8];
    *(half8*)&As[r][c8 * 8] = v;
  }
  __syncthreads();
  const int w = t >> 6, l = t & 63;
  const int c = l & 15, quad = l >> 4;
  f32x4 acc[8];
#pragma unroll
  for (int nt = 0; nt < 8; ++nt) acc[nt] = (f32x4){0.f, 0.f, 0.f, 0.f};
#pragma unroll
  for (int kc = 0; kc < 4; ++kc) {
    half8 a = *(const half8*)&As[w * 16 + c][kc * 32 + quad * 8];
#pragma unroll
    for (int nt = 0; nt < 8; ++nt) {
      half8 b = *(const half8*)&Wt[(size_t)(nt * 16 + c) * 128 + kc * 32 + quad * 8];
      acc[nt] = __builtin_amdgcn_mfma_f32_16x16x32_f16(a, b, acc[nt], 0, 0, 0);
    }
  }
#pragma unroll
  for (int nt = 0; nt < 8; ++nt)
#pragma unroll
    for (int r = 0; r < 4; ++r)
      Cs[w * 16 + quad * 4 + r][nt * 16 + c] = (_Float16)acc[nt][r];
  __syncthreads();
  for (int i = t; i < 64 * 16; i += 256) {
    int r = i >> 4, c8 = i & 15;
    if (r0 + r < N)
      ((half8*)C)[(size_t)(r0 + r) * 16 + c8] = *(half8*)&Cs[r][c8 * 8];
  }
}

// ---------------- gather core ----------------
#define PK_ROW(u)                                                           \
  _Pragma("unroll")                                                         \
  for (int k = 0; k < 4; ++k) acch[k] += (u).h[k];

__device__ __forceinline__ void gather_core(const half8* __restrict__ P8,
                                            const int* __restrict__ csr,
                                            int start, int end, int cg, int eg,
                                            int lane, float* acc) {
  half2v acch[4] = {{(_Float16)0.f, (_Float16)0.f}, {(_Float16)0.f, (_Float16)0.f},
                    {(_Float16)0.f, (_Float16)0.f}, {(_Float16)0.f, (_Float16)0.f}};
  for (int s0 = start; s0 < end; s0 += 64) {
    int cnt = min(64, end - s0);
    int idx = (s0 + lane < end) ? csr[s0 + lane] : 0;
    int base = 0;
    for (; base + 16 <= cnt; base += 16) {
      int i0 = __shfl(idx, base + eg);
      int i1 = __shfl(idx, base + 4 + eg);
      int i2 = __shfl(idx, base + 8 + eg);
      int i3 = __shfl(idx, base + 12 + eg);
      H8 u0, u1, u2, u3;
      u0.v = P8[(size_t)i0 * 16 + cg];
      u1.v = P8[(size_t)i1 * 16 + cg];
      u2.v = P8[(size_t)i2 * 16 + cg];
      u3.v = P8[(size_t)i3 * 16 + cg];
      PK_ROW(u0) PK_ROW(u1) PK_ROW(u2) PK_ROW(u3)
    }
    for (; base + 4 <= cnt; base += 4) {
      int i0 = __shfl(idx, base + eg);
      H8 u0;
      u0.v = P8[(size_t)i0 * 16 + cg];
      PK_ROW(u0)
    }
    if (base < cnt) {  // 1-3 tail edges
      int j = min(base + eg, cnt - 1);
      int i0 = __shfl(idx, j);
      if (base + eg < cnt) {
        H8 u0;
        u0.v = P8[(size_t)i0 * 16 + cg];
        PK_ROW(u0)
      }
    }
  }
#pragma unroll
  for (int k = 0; k < 4; ++k) {
    acc[2 * k]     = (float)acch[k].x;
    acc[2 * k + 1] = (float)acch[k].y;
  }
#pragma unroll
  for (int j = 0; j < 8; ++j) {
    acc[j] += __shfl_xor(acc[j], 16);
    acc[j] += __shfl_xor(acc[j], 32);
  }
}

// gather 1: h1' = norm_src * relu(agg*nd + b), fp16 out
__global__ __launch_bounds__(256) void k_gather1(const half8* __restrict__ P8,
                                                 const int* __restrict__ row_lo,
                                                 const int* __restrict__ row_hi,
                                                 const int* __restrict__ csr,
                                                 const float* __restrict__ bias,
                                                 const float* __restrict__ norm_src,
                                                 half2v* __restrict__ outH, int N) {
  int wid = (blockIdx.x * 256 + threadIdx.x) >> 6;
  if (wid >= N) return;
  int lane = threadIdx.x & 63;
  int cg = lane & 15, eg = lane >> 4;
  int start = row_lo[wid], end = row_hi[wid];
  float acc[8];
  gather_core(P8, csr, start, end, cg, eg, lane, acc);
  float nd = rsqrtf(fmaxf((float)(end - start), 1.0f));
  float ns = norm_src[wid];
  float2 b = ((const float2*)bias)[cg * 4 + eg];
  half2v o = {(_Float16)(fmaxf(acc[eg * 2] * nd + b.x, 0.f) * ns),
              (_Float16)(fmaxf(acc[eg * 2 + 1] * nd + b.y, 0.f) * ns)};
  outH[(size_t)wid * 64 + cg * 4 + eg] = o;
}

// gather 2: h2 = relu(agg*nd + b), fp32 out
__global__ __launch_bounds__(256) void k_gather2(const half8* __restrict__ P8,
                                                 const int* __restrict__ row_lo,
                                                 const int* __restrict__ row_hi,
                                                 const int* __restrict__ csr,
                                                 const float* __restrict__ bias,
                                                 float2* __restrict__ outH, int N) {
  int wid = (blockIdx.x * 256 + threadIdx.x) >> 6;
  if (wid >= N) return;
  int lane = threadIdx.x & 63;
  int cg = lane & 15, eg = lane >> 4;
  int start = row_lo[wid], end = row_hi[wid];
  float acc[8];
  gather_core(P8, csr, start, end, cg, eg, lane, acc);
  float nd = rsqrtf(fmaxf((float)(end - start), 1.0f));
  float2 b = ((const float2*)bias)[cg * 4 + eg];
  float2 o;
  o.x = fmaxf(acc[eg * 2] * nd + b.x, 0.f);
  o.y = fmaxf(acc[eg * 2 + 1] * nd + b.y, 0.f);
  outH[(size_t)wid * 64 + cg * 4 + eg] = o;
}

// ================= cooperative tail kernel: pool + readout ==================
__global__ __launch_bounds__(256, 2) void k_tail(
    const float* __restrict__ H, const int* __restrict__ gptr,
    float* __restrict__ pool,
    const float* __restrict__ Wr1, const float* __restrict__ br1,
    const float* __restrict__ Wr2, const float* __restrict__ br2,
    float* __restrict__ out) {
  cooperative_groups::grid_group grid = cooperative_groups::this_grid();
  const int t = threadIdx.x;
  const int bid = blockIdx.x;
  const int G = gridDim.x;
  __shared__ float red[256];
  __shared__ float hg[128];
  __shared__ float t1[128];

  for (int task = bid; task < 512; task += G) {
    int g = task >> 3, chunk = task & 7;
    int col = t & 127, rpar = t >> 7;
    int s = gptr[g], e = gptr[g + 1];
    float acc = 0.0f;
    for (int r = s + chunk * 2 + rpar; r < e; r += 16)
      acc += H[(size_t)r * D + col];
    red[t] = acc;
    __syncthreads();
    if (rpar == 0) atomicAdd(&pool[g * D + col], acc + red[t + 128]);
    __syncthreads();
  }
  grid.sync();
  for (int g = bid; g < 64; g += G) {
    float cnt = fmaxf((float)(gptr[g + 1] - gptr[g]), 1.0f);
    if (t < 128) hg[t] = pool[(size_t)g * D + t] / cnt;
    __syncthreads();
    if (t < 128) {
      float a = br1[t];
      for (int k = 0; k < D; ++k) a += hg[k] * Wr1[(size_t)k * D + t];
      t1[t] = fmaxf(a, 0.0f);
    }
    __syncthreads();
    if (t < 128) {
      float b = br2[t];
      for (int k = 0; k < D; ++k) b += t1[k] * Wr2[(size_t)k * D + t];
      out[(size_t)g * D + t] = b;
    }
    __syncthreads();
  }
}

extern "C" void kernel_launch(void* const* d_in, const int* in_sizes, int n_in,
                              void* d_out, int out_size, void* d_ws, size_t ws_size,
                              hipStream_t stream) {
  const float* x   = (const float*)d_in[0];
  const int* edge  = (const int*)d_in[1];
  const int* gid   = (const int*)d_in[2];
  const float* W1  = (const float*)d_in[4];
  const float* b1  = (const float*)d_in[5];
  const float* W2  = (const float*)d_in[6];
  const float* b2  = (const float*)d_in[7];
  const float* Wr1 = (const float*)d_in[8];
  const float* br1 = (const float*)d_in[9];
  const float* Wr2 = (const float*)d_in[10];
  const float* br2 = (const float*)d_in[11];

  const int N = in_sizes[0] / D;   // 100000
  const int E = in_sizes[1] / 2;   // 1600000
  const int* src = edge;
  const int* dst = edge + E;
  const int nbkt = (N + BKT - 1) >> BSH;  // 391

  // workspace layout
  float* bufA     = (float*)d_ws;                    // P (half N*128) lives here
  float* bufB     = bufA + (size_t)N * D;            // h1' (half N*128) lives here
  int* row_lo     = (int*)(bufB + (size_t)N * D);    // N
  int* row_hi     = row_lo + N;                      // N
  int* csr        = row_hi + N;                      // nbkt*CAP (bucket-padded)
  float* norm_src = (float*)(csr + (size_t)nbkt * CAP);  // N
  float* pool     = norm_src + N;                    // 64*128
  int* gptr       = (int*)(pool + 64 * D);           // 65
  int* cnt_d      = gptr + 65;                       // 512
  int* cnt_s      = cnt_d + 512;                     // 512 (adjacent)
  _Float16* Wt1   = (_Float16*)(cnt_s + 512);        // 128*128 halves
  _Float16* Wt2   = Wt1 + 128 * 128;                 // 128*128 halves
  // temporaries aliasing bufA (consumed by k_fine before gemm1 writes P)
  int* packed_d   = (int*)bufA;                      // nbkt*CAP
  int* packed_s   = packed_d + (size_t)nbkt * CAP;   // nbkt*CAP
  size_t need = ((size_t)2 * N * D + 3 * (size_t)N + (size_t)nbkt * CAP
                 + 64 * D + 65 + 1024 + 16384 + 1024) * sizeof(float);
  if (ws_size < need) return;

  float* out_g = (float*)d_out;      // 64*128
  float* h_out = out_g + 64 * D;     // N*128

  _Float16* P   = (_Float16*)bufA;
  _Float16* h1p = (_Float16*)bufB;

  // cached cooperative grid size for k_tail (co-residency-safe)
  static int G2 = 0;
  if (G2 == 0) {
    int occ2 = 0, ncu = 256;
    hipOccupancyMaxActiveBlocksPerMultiprocessor(&occ2, k_tail, 256, 0);
    hipDeviceProp_t prop;
    int dev = 0;
    if (hipGetDevice(&dev) == hipSuccess &&
        hipGetDeviceProperties(&prop, dev) == hipSuccess &&
        prop.multiProcessorCount > 0)
      ncu = prop.multiProcessorCount;
    G2 = (occ2 > 0) ? min(512, occ2 * ncu) : 512;
  }

  // prep: Wt transpose + zero cnt_d/cnt_s/pool + gptr bsearch (block 128)
  k_prep<<<129, 256, 0, stream>>>(W1, W2, Wt1, Wt2, cnt_d, pool, gid, gptr, N);

  // graph structure: merged histogram+scatter, then per-bucket fine sort
  const int build_grid = (E + SCHUNK - 1) / SCHUNK;  // 500
  k_build<<<build_grid, 512, 0, stream>>>(src, dst, cnt_d, cnt_s,
                                          packed_d, packed_s, E, nbkt);
  k_fine<<<2 * nbkt, 512, 0, stream>>>(packed_d, cnt_d, row_lo, row_hi, csr,
                                       packed_s, cnt_s, norm_src, N, nbkt);

  const int gemm_grid = (N + 63) / 64;

  // layer 1
  k_gemm1<<<gemm_grid, 256, 0, stream>>>(x, Wt1, norm_src, P, N);
  k_gather1<<<(N * 64 + 255) / 256, 256, 0, stream>>>(
      (const half8*)P, row_lo, row_hi, csr, b1, norm_src, (half2v*)h1p, N);

  // layer 2
  k_gemm2<<<gemm_grid, 256, 0, stream>>>(h1p, Wt2, P, N);
  k_gather2<<<(N * 64 + 255) / 256, 256, 0, stream>>>(
      (const half8*)P, row_lo, row_hi, csr, b2, (float2*)h_out, N);

  // tail: pool + readout (cooperative, trivial-VGPR)
  {
    void* args[] = {
      (void*)&h_out, (void*)&gptr, (void*)&pool,
      (void*)&Wr1, (void*)&br1, (void*)&Wr2, (void*)&br2, (void*)&out_g};
    hipLaunchCooperativeKernel(k_tail, dim3(G2), dim3(256), args, 0, stream);
  }
}

// Round 8
// 418.671 us; speedup vs baseline: 1.6270x; 1.1072x over previous
//
#include <hip/hip_runtime.h>
#include <math.h>

// GCN: h1 = relu(norm_dst * A * (norm_src * x) @ W1 + b1)
//      h2 = relu(norm_dst * A * (norm_src * h1) @ W2 + b2)
//      hg = mean_per_graph(h2); out = relu(hg@Wr1+br1)@Wr2+br2
// d_out = [out (64*128) | h2 (N*128)]
//
// R2-R9: CSR-by-dst + register gather; two-level counting sort; fp16 MFMA
//        pipeline. Gather pinned at ~60us random-read floor (3.9 TB/s).
// R10/R11: FAILED - deg via random global atomics (+48us memory-side RMW).
// R12: bucket 512->256 neutral (411). R13: merged build + padded buckets +
//        LDS-sorted coalesced csr: 383us.
// R15: FAILED - cooperative k_graph: launch_bounds(256,4) capped VGPR at 60,
//        gemm1 acc spilled (WRITE 125MB): 681us. Lesson: never fuse high-VGPR
//        MFMA with low-VGPR phases under one launch bound.
// R16: FAILED - cooperative k_tail(pool+readout) = 83us vs ~25us separate;
//        VALUBusy 1.6%. Lesson: grid.sync costs ~30-50us here - MORE than a
//        ~10us dispatch boundary. Cooperative fusion abandoned.
// R17: revert to R13 structure. k_prep deleted (Wt transpose + gptr folded
//        into k_build grid-stride prologue; cnt/pool zeroed via 2 tiny
//        hipMemsetAsync DMAs). k_build: no LDS edge staging (2nd pass
//        re-reads edges L2-hot), 256thr x 1024 blocks, LDS 8KB -> ~8
//        blocks/CU for latency hiding of scattered writes + atomics.
// Assumes N <= 131072 (src fits 17 bits in packing).

#define D 128
#define BSH 8
#define BKT 256      // nodes per bucket
#define CAP 4608     // padded bucket capacity (avg 4096, sigma 64 -> +8 sigma)
#define BGRID 1024   // k_build grid

typedef _Float16 half8 __attribute__((ext_vector_type(8)));
typedef _Float16 half4v __attribute__((ext_vector_type(4)));
typedef _Float16 half2v __attribute__((ext_vector_type(2)));
typedef float f32x4 __attribute__((ext_vector_type(4)));

union H8 { half8 v; half2v h[4]; };

// -------- build: Wt/gptr prologue + histogram + slot reserve + scatter --------
__global__ __launch_bounds__(256) void k_build(const int* __restrict__ src,
                                               const int* __restrict__ dst,
                                               int* __restrict__ cnt_d,
                                               int* __restrict__ cnt_s,
                                               int* __restrict__ packed_d,
                                               int* __restrict__ packed_s,
                                               const float* __restrict__ W1,
                                               const float* __restrict__ W2,
                                               _Float16* __restrict__ Wt1,
                                               _Float16* __restrict__ Wt2,
                                               const int* __restrict__ gid,
                                               int* __restrict__ gptr,
                                               int N, int E, int nbkt) {
  __shared__ int hd[512], hs[512], based[512], bases[512];
  const int t = threadIdx.x;
  const int bid = blockIdx.x;

  // prologue: Wt transpose (blocks 0-127 active), gptr bsearch (last block)
  for (int idx = bid * 256 + t; idx < 2 * 128 * 128; idx += gridDim.x * 256) {
    int m = idx >> 14, i = idx & 16383;
    int k = i >> 7, n = i & 127;
    (m ? Wt2 : Wt1)[n * 128 + k] = (_Float16)((m ? W2 : W1)[i]);
  }
  if (bid == gridDim.x - 1 && t <= 64) {  // gptr[g] = lower_bound(gid, g)
    int lo = 0, hi = N;
    while (lo < hi) {
      int m = (lo + hi) >> 1;
      if (gid[m] < t) lo = m + 1; else hi = m;
    }
    gptr[t] = lo;
  }

  hd[t] = 0; hd[t + 256] = 0;
  hs[t] = 0; hs[t + 256] = 0;
  __syncthreads();
  int chunk = (E + gridDim.x - 1) / gridDim.x;
  int lo = bid * chunk, hi = min(lo + chunk, E);
  for (int i = lo + t; i < hi; i += 256) {
    atomicAdd(&hd[dst[i] >> BSH], 1);
    atomicAdd(&hs[src[i] >> BSH], 1);
  }
  __syncthreads();
  int c0d = hd[t], c1d = hd[t + 256];
  int c0s = hs[t], c1s = hs[t + 256];
  __syncthreads();
  hd[t] = 0; hd[t + 256] = 0;   // reuse as rank counters
  hs[t] = 0; hs[t + 256] = 0;
  if (t < nbkt)       based[t]       = c0d ? atomicAdd(&cnt_d[t], c0d) : 0;
  if (t + 256 < nbkt) based[t + 256] = c1d ? atomicAdd(&cnt_d[t + 256], c1d) : 0;
  if (t < nbkt)       bases[t]       = c0s ? atomicAdd(&cnt_s[t], c0s) : 0;
  if (t + 256 < nbkt) bases[t + 256] = c1s ? atomicAdd(&cnt_s[t + 256], c1s) : 0;
  __syncthreads();
  for (int i = lo + t; i < hi; i += 256) {   // re-read chunk (L2-hot)
    int s = src[i], d = dst[i];
    int b1 = d >> BSH;
    int p1 = based[b1] + atomicAdd(&hd[b1], 1);
    if (p1 < CAP) packed_d[b1 * CAP + p1] = ((d & (BKT - 1)) << 17) | s;
    int b2 = s >> BSH;
    int p2 = bases[b2] + atomicAdd(&hs[b2], 1);
    if (p2 < CAP) packed_s[b2 * CAP + p2] = s & (BKT - 1);
  }
}

// ---------------- fine pass: blocks [0,nbkt) dst, [nbkt,2*nbkt) src ----------
// dst: per-bucket counting sort fully in LDS; csr written coalesced.
__global__ __launch_bounds__(512) void k_fine(const int* __restrict__ packed_d,
                                              const int* __restrict__ cnt_d,
                                              int* __restrict__ row_lo,
                                              int* __restrict__ row_hi,
                                              int* __restrict__ csr,
                                              const int* __restrict__ packed_s,
                                              const int* __restrict__ cnt_s,
                                              float* __restrict__ norm_src,
                                              int N, int nbkt) {
  __shared__ int hist[256];
  int t = threadIdx.x;
  if (blockIdx.x >= nbkt) {
    // ---- src side: norm_src = rsqrt(max(deg_out,1)) ----
    int b = blockIdx.x - nbkt;
    int lo = b * CAP;
    int cnt = min(cnt_s[b], CAP);
    if (t < 256) hist[t] = 0;
    __syncthreads();
    for (int e = t; e < cnt; e += 512)
      atomicAdd(&hist[packed_s[lo + e]], 1);
    __syncthreads();
    int nbase = b << BSH;
    if (t < 256 && nbase + t < N)
      norm_src[nbase + t] = rsqrtf(fmaxf((float)hist[t], 1.0f));
    return;
  }
  // ---- dst side: row_lo/row_hi + csr ----
  __shared__ int excl[256];
  __shared__ int ecache[CAP];
  __shared__ int sorted[CAP];
  int b = blockIdx.x;
  int lo = b * CAP;
  int cnt = min(cnt_d[b], CAP);
  if (t < 256) hist[t] = 0;
  __syncthreads();
  for (int e = t; e < cnt; e += 512) {
    int p = packed_d[lo + e];
    ecache[e] = p;
    atomicAdd(&hist[p >> 17], 1);
  }
  __syncthreads();
  int v = (t < 256) ? hist[t] : 0;
  // inclusive scan of hist (256 entries; all threads hit barriers)
  for (int off = 1; off < 256; off <<= 1) {
    int a = (t >= off && t < 256) ? hist[t - off] : 0;
    __syncthreads();
    if (t < 256) hist[t] += a;
    __syncthreads();
  }
  int nbase = b << BSH;
  if (t < 256) {
    excl[t] = hist[t] - v;
    if (nbase + t < N) {
      row_lo[nbase + t] = lo + hist[t] - v;
      row_hi[nbase + t] = lo + hist[t];
    }
  }
  __syncthreads();
  if (t < 256) hist[t] = 0;  // reuse as rank counters
  __syncthreads();
  for (int e = t; e < cnt; e += 512) {
    int p = ecache[e];
    int dlow = p >> 17;
    int r = atomicAdd(&hist[dlow], 1);
    sorted[excl[dlow] + r] = p & 0x1FFFF;
  }
  __syncthreads();
  for (int e = t; e < cnt; e += 512)   // coalesced csr write
    csr[lo + e] = sorted[e];
}

// ---------------- MFMA GEMM (fp32 input): C(half) = (scale*A)@W ----------------
__global__ __launch_bounds__(256) void k_gemm1(const float* __restrict__ A,
                                               const _Float16* __restrict__ Wt,
                                               const float* __restrict__ scale,
                                               _Float16* __restrict__ C, int N) {
  __shared__ _Float16 As[64][136];
  __shared__ _Float16 Cs[64][128];
  const int r0 = blockIdx.x * 64;
  const int t = threadIdx.x;
  for (int i = t; i < 64 * 32; i += 256) {
    int r = i >> 5, c4 = i & 31;
    float4 v = {0.f, 0.f, 0.f, 0.f};
    if (r0 + r < N) {
      v = ((const float4*)A)[(size_t)(r0 + r) * 32 + c4];
      float s = scale[r0 + r];
      v.x *= s; v.y *= s; v.z *= s; v.w *= s;
    }
    half4v h = {(_Float16)v.x, (_Float16)v.y, (_Float16)v.z, (_Float16)v.w};
    *(half4v*)&As[r][c4 * 4] = h;
  }
  __syncthreads();
  const int w = t >> 6, l = t & 63;
  const int c = l & 15, quad = l >> 4;
  f32x4 acc[8];
#pragma unroll
  for (int nt = 0; nt < 8; ++nt) acc[nt] = (f32x4){0.f, 0.f, 0.f, 0.f};
#pragma unroll
  for (int kc = 0; kc < 4; ++kc) {
    half8 a = *(const half8*)&As[w * 16 + c][kc * 32 + quad * 8];
#pragma unroll
    for (int nt = 0; nt < 8; ++nt) {
      half8 b = *(const half8*)&Wt[(size_t)(nt * 16 + c) * 128 + kc * 32 + quad * 8];
      acc[nt] = __builtin_amdgcn_mfma_f32_16x16x32_f16(a, b, acc[nt], 0, 0, 0);
    }
  }
#pragma unroll
  for (int nt = 0; nt < 8; ++nt)
#pragma unroll
    for (int r = 0; r < 4; ++r)
      Cs[w * 16 + quad * 4 + r][nt * 16 + c] = (_Float16)acc[nt][r];
  __syncthreads();
  for (int i = t; i < 64 * 16; i += 256) {
    int r = i >> 4, c8 = i & 15;
    if (r0 + r < N)
      ((half8*)C)[(size_t)(r0 + r) * 16 + c8] = *(half8*)&Cs[r][c8 * 8];
  }
}

// ---------------- MFMA GEMM (fp16 pre-scaled input): C(half) = A@W -----------
__global__ __launch_bounds__(256) void k_gemm2(const _Float16* __restrict__ A,
                                               const _Float16* __restrict__ Wt,
                                               _Float16* __restrict__ C, int N) {
  __shared__ _Float16 As[64][136];
  __shared__ _Float16 Cs[64][128];
  const int r0 = blockIdx.x * 64;
  const int t = threadIdx.x;
  for (int i = t; i < 64 * 16; i += 256) {
    int r = i >> 4, c8 = i & 15;
    half8 v = {0, 0, 0, 0, 0, 0, 0, 0};
    if (r0 + r < N) v = ((const half8*)A)[(size_t)(r0 + r) * 16 + c8];
    *(half8*)&As[r][c8 * 8] = v;
  }
  __syncthreads();
  const int w = t >> 6, l = t & 63;
  const int c = l & 15, quad = l >> 4;
  f32x4 acc[8];
#pragma unroll
  for (int nt = 0; nt < 8; ++nt) acc[nt] = (f32x4){0.f, 0.f, 0.f, 0.f};
#pragma unroll
  for (int kc = 0; kc < 4; ++kc) {
    half8 a = *(const half8*)&As[w * 16 + c][kc * 32 + quad * 8];
#pragma unroll
    for (int nt = 0; nt < 8; ++nt) {
      half8 b = *(const half8*)&Wt[(size_t)(nt * 16 + c) * 128 + kc * 32 + quad * 8];
      acc[nt] = __builtin_amdgcn_mfma_f32_16x16x32_f16(a, b, acc[nt], 0, 0, 0);
    }
  }
#pragma unroll
  for (int nt = 0; nt < 8; ++nt)
#pragma unroll
    for (int r = 0; r < 4; ++r)
      Cs[w * 16 + quad * 4 + r][nt * 16 + c] = (_Float16)acc[nt][r];
  __syncthreads();
  for (int i = t; i < 64 * 16; i += 256) {
    int r = i >> 4, c8 = i & 15;
    if (r0 + r < N)
      ((half8*)C)[(size_t)(r0 + r) * 16 + c8] = *(half8*)&Cs[r][c8 * 8];
  }
}

// ---------------- gather core ----------------
#define PK_ROW(u)                                                           \
  _Pragma("unroll")                                                         \
  for (int k = 0; k < 4; ++k) acch[k] += (u).h[k];

__device__ __forceinline__ void gather_core(const half8* __restrict__ P8,
                                            const int* __restrict__ csr,
                                            int start, int end, int cg, int eg,
                                            int lane, float* acc) {
  half2v acch[4] = {{(_Float16)0.f, (_Float16)0.f}, {(_Float16)0.f, (_Float16)0.f},
                    {(_Float16)0.f, (_Float16)0.f}, {(_Float16)0.f, (_Float16)0.f}};
  for (int s0 = start; s0 < end; s0 += 64) {
    int cnt = min(64, end - s0);
    int idx = (s0 + lane < end) ? csr[s0 + lane] : 0;
    int base = 0;
    for (; base + 16 <= cnt; base += 16) {
      int i0 = __shfl(idx, base + eg);
      int i1 = __shfl(idx, base + 4 + eg);
      int i2 = __shfl(idx, base + 8 + eg);
      int i3 = __shfl(idx, base + 12 + eg);
      H8 u0, u1, u2, u3;
      u0.v = P8[(size_t)i0 * 16 + cg];
      u1.v = P8[(size_t)i1 * 16 + cg];
      u2.v = P8[(size_t)i2 * 16 + cg];
      u3.v = P8[(size_t)i3 * 16 + cg];
      PK_ROW(u0) PK_ROW(u1) PK_ROW(u2) PK_ROW(u3)
    }
    for (; base + 4 <= cnt; base += 4) {
      int i0 = __shfl(idx, base + eg);
      H8 u0;
      u0.v = P8[(size_t)i0 * 16 + cg];
      PK_ROW(u0)
    }
    if (base < cnt) {  // 1-3 tail edges
      int j = min(base + eg, cnt - 1);
      int i0 = __shfl(idx, j);
      if (base + eg < cnt) {
        H8 u0;
        u0.v = P8[(size_t)i0 * 16 + cg];
        PK_ROW(u0)
      }
    }
  }
#pragma unroll
  for (int k = 0; k < 4; ++k) {
    acc[2 * k]     = (float)acch[k].x;
    acc[2 * k + 1] = (float)acch[k].y;
  }
#pragma unroll
  for (int j = 0; j < 8; ++j) {
    acc[j] += __shfl_xor(acc[j], 16);
    acc[j] += __shfl_xor(acc[j], 32);
  }
}

// gather 1: h1' = norm_src * relu(agg*nd + b), fp16 out
__global__ __launch_bounds__(256) void k_gather1(const half8* __restrict__ P8,
                                                 const int* __restrict__ row_lo,
                                                 const int* __restrict__ row_hi,
                                                 const int* __restrict__ csr,
                                                 const float* __restrict__ bias,
                                                 const float* __restrict__ norm_src,
                                                 half2v* __restrict__ outH, int N) {
  int wid = (blockIdx.x * 256 + threadIdx.x) >> 6;
  if (wid >= N) return;
  int lane = threadIdx.x & 63;
  int cg = lane & 15, eg = lane >> 4;
  int start = row_lo[wid], end = row_hi[wid];
  float acc[8];
  gather_core(P8, csr, start, end, cg, eg, lane, acc);
  float nd = rsqrtf(fmaxf((float)(end - start), 1.0f));
  float ns = norm_src[wid];
  float2 b = ((const float2*)bias)[cg * 4 + eg];
  half2v o = {(_Float16)(fmaxf(acc[eg * 2] * nd + b.x, 0.f) * ns),
              (_Float16)(fmaxf(acc[eg * 2 + 1] * nd + b.y, 0.f) * ns)};
  outH[(size_t)wid * 64 + cg * 4 + eg] = o;
}

// gather 2: h2 = relu(agg*nd + b), fp32 out
__global__ __launch_bounds__(256) void k_gather2(const half8* __restrict__ P8,
                                                 const int* __restrict__ row_lo,
                                                 const int* __restrict__ row_hi,
                                                 const int* __restrict__ csr,
                                                 const float* __restrict__ bias,
                                                 float2* __restrict__ outH, int N) {
  int wid = (blockIdx.x * 256 + threadIdx.x) >> 6;
  if (wid >= N) return;
  int lane = threadIdx.x & 63;
  int cg = lane & 15, eg = lane >> 4;
  int start = row_lo[wid], end = row_hi[wid];
  float acc[8];
  gather_core(P8, csr, start, end, cg, eg, lane, acc);
  float nd = rsqrtf(fmaxf((float)(end - start), 1.0f));
  float2 b = ((const float2*)bias)[cg * 4 + eg];
  float2 o;
  o.x = fmaxf(acc[eg * 2] * nd + b.x, 0.f);
  o.y = fmaxf(acc[eg * 2 + 1] * nd + b.y, 0.f);
  outH[(size_t)wid * 64 + cg * 4 + eg] = o;
}

// ---------------- segment-sum pooling over sorted graph_id ----------------
__global__ __launch_bounds__(256) void k_pool(const float* __restrict__ H,
                                              const int* __restrict__ gptr,
                                              float* __restrict__ pool) {
  int g = blockIdx.x >> 3, chunk = blockIdx.x & 7;
  int col = threadIdx.x & 127, rpar = threadIdx.x >> 7;
  int s = gptr[g], e = gptr[g + 1];
  float acc = 0.0f;
  for (int r = s + chunk * 2 + rpar; r < e; r += 16)
    acc += H[(size_t)r * D + col];
  __shared__ float red[256];
  red[threadIdx.x] = acc;
  __syncthreads();
  if (rpar == 0) atomicAdd(&pool[g * D + col], acc + red[threadIdx.x + 128]);
}

// ---------------- readout MLP ----------------
__global__ __launch_bounds__(128) void k_readout(const float* __restrict__ pool,
                                                 const int* __restrict__ gptr,
                                                 const float* __restrict__ Wr1,
                                                 const float* __restrict__ br1,
                                                 const float* __restrict__ Wr2,
                                                 const float* __restrict__ br2,
                                                 float* __restrict__ out) {
  int g = blockIdx.x;
  int j = threadIdx.x;
  __shared__ float hg[D];
  __shared__ float t1[D];
  float cnt = fmaxf((float)(gptr[g + 1] - gptr[g]), 1.0f);
  hg[j] = pool[(size_t)g * D + j] / cnt;
  __syncthreads();
  float a = br1[j];
  for (int k = 0; k < D; ++k) a += hg[k] * Wr1[(size_t)k * D + j];
  t1[j] = fmaxf(a, 0.0f);
  __syncthreads();
  float b = br2[j];
  for (int k = 0; k < D; ++k) b += t1[k] * Wr2[(size_t)k * D + j];
  out[(size_t)g * D + j] = b;
}

extern "C" void kernel_launch(void* const* d_in, const int* in_sizes, int n_in,
                              void* d_out, int out_size, void* d_ws, size_t ws_size,
                              hipStream_t stream) {
  const float* x   = (const float*)d_in[0];
  const int* edge  = (const int*)d_in[1];
  const int* gid   = (const int*)d_in[2];
  const float* W1  = (const float*)d_in[4];
  const float* b1  = (const float*)d_in[5];
  const float* W2  = (const float*)d_in[6];
  const float* b2  = (const float*)d_in[7];
  const float* Wr1 = (const float*)d_in[8];
  const float* br1 = (const float*)d_in[9];
  const float* Wr2 = (const float*)d_in[10];
  const float* br2 = (const float*)d_in[11];

  const int N = in_sizes[0] / D;   // 100000
  const int E = in_sizes[1] / 2;   // 1600000
  const int* src = edge;
  const int* dst = edge + E;
  const int nbkt = (N + BKT - 1) >> BSH;  // 391

  // workspace layout
  float* bufA     = (float*)d_ws;                    // P (half N*128) lives here
  float* bufB     = bufA + (size_t)N * D;            // h1' (half N*128) lives here
  int* row_lo     = (int*)(bufB + (size_t)N * D);    // N
  int* row_hi     = row_lo + N;                      // N
  int* csr        = row_hi + N;                      // nbkt*CAP (bucket-padded)
  float* norm_src = (float*)(csr + (size_t)nbkt * CAP);  // N
  float* pool     = norm_src + N;                    // 64*128
  int* gptr       = (int*)(pool + 64 * D);           // 65
  int* cnt_d      = gptr + 65;                       // 512
  int* cnt_s      = cnt_d + 512;                     // 512 (adjacent)
  _Float16* Wt1   = (_Float16*)(cnt_s + 512);        // 128*128 halves
  _Float16* Wt2   = Wt1 + 128 * 128;                 // 128*128 halves
  // temporaries aliasing bufA (consumed by k_fine before gemm1 writes P)
  int* packed_d   = (int*)bufA;                      // nbkt*CAP
  int* packed_s   = packed_d + (size_t)nbkt * CAP;   // nbkt*CAP
  size_t need = ((size_t)2 * N * D + 3 * (size_t)N + (size_t)nbkt * CAP
                 + 64 * D + 65 + 1024 + 16384 + 1024) * sizeof(float);
  if (ws_size < need) return;

  float* out_g = (float*)d_out;      // 64*128
  float* h_out = out_g + 64 * D;     // N*128

  _Float16* P   = (_Float16*)bufA;
  _Float16* h1p = (_Float16*)bufB;

  // zero cnt_d/cnt_s (4KB) and pool (32KB) via DMA
  hipMemsetAsync(cnt_d, 0, 1024 * sizeof(int), stream);
  hipMemsetAsync(pool, 0, 64 * D * sizeof(float), stream);

  // build: Wt/gptr prologue + histogram + slot reserve + scatter
  k_build<<<BGRID, 256, 0, stream>>>(src, dst, cnt_d, cnt_s, packed_d, packed_s,
                                     W1, W2, Wt1, Wt2, gid, gptr, N, E, nbkt);
  k_fine<<<2 * nbkt, 512, 0, stream>>>(packed_d, cnt_d, row_lo, row_hi, csr,
                                       packed_s, cnt_s, norm_src, N, nbkt);

  const int gemm_grid = (N + 63) / 64;

  // layer 1
  k_gemm1<<<gemm_grid, 256, 0, stream>>>(x, Wt1, norm_src, P, N);
  k_gather1<<<(N * 64 + 255) / 256, 256, 0, stream>>>(
      (const half8*)P, row_lo, row_hi, csr, b1, norm_src, (half2v*)h1p, N);

  // layer 2
  k_gemm2<<<gemm_grid, 256, 0, stream>>>(h1p, Wt2, P, N);
  k_gather2<<<(N * 64 + 255) / 256, 256, 0, stream>>>(
      (const half8*)P, row_lo, row_hi, csr, b2, (float2*)h_out, N);

  // pooling + readout
  k_pool<<<64 * 8, 256, 0, stream>>>(h_out, gptr, pool);
  k_readout<<<64, 128, 0, stream>>>(pool, gptr, Wr1, br1, Wr2, br2, out_g);
}

// Round 9
// 381.223 us; speedup vs baseline: 1.7868x; 1.0982x over previous
//
#include <hip/hip_runtime.h>
#include <math.h>

// GCN: h1 = relu(norm_dst * A * (norm_src * x) @ W1 + b1)
//      h2 = relu(norm_dst * A * (norm_src * h1) @ W2 + b2)
//      hg = mean_per_graph(h2); out = relu(hg@Wr1+br1)@Wr2+br2
// d_out = [out (64*128) | h2 (N*128)]
//
// R2-R9: CSR-by-dst + register gather; two-level counting sort; fp16 MFMA
//        pipeline. Gather pinned at ~60us random-read floor (3.9 TB/s).
// R10/R11: FAILED - deg via random global atomics (+48us, 32B/op memory-side).
// R13: merged build + padded buckets + LDS-sorted coalesced csr: 383us.
// R15: FAILED - coop k_graph: launch_bounds(256,4) spilled gemm acc: 681us.
// R16: FAILED - coop k_tail: grid.sync costs ~30-50us > 10us boundary: 463us.
// R17: 418us. PMC smoking gun: k_build WRITE_SIZE 92MB vs 13MB logical -
//        every scattered 4B packed store = 32B memory-side sector.
// R18: run-coalesced k_build. Rank-scatter packed values into LDS in
//        bucket-sorted order, then LINEAR flush (binary-search bucket, write
//        packed[b*CAP+based[b]+(i-excl[b])]): runs of ~8 consecutive slots
//        -> 1-2 sectors/run instead of 8. packed_s shrunk to 1 byte/edge.
//        Single memset span (pool|gptr|cnt). 8 queue items.
// Assumes N <= 131072 (src fits 17 bits in packing).

#define D 128
#define BSH 8
#define BKT 256      // nodes per bucket
#define CAP 4608     // padded bucket capacity (avg 4096, sigma 64 -> +8 sigma)
#define SCHUNK 3200  // edges per build block

typedef _Float16 half8 __attribute__((ext_vector_type(8)));
typedef _Float16 half4v __attribute__((ext_vector_type(4)));
typedef _Float16 half2v __attribute__((ext_vector_type(2)));
typedef float f32x4 __attribute__((ext_vector_type(4)));

union H8 { half8 v; half2v h[4]; };

// -------- build: histogram + scan + slot reserve + LDS sort + linear flush ---
__global__ __launch_bounds__(512) void k_build(const int* __restrict__ src,
                                               const int* __restrict__ dst,
                                               int* __restrict__ cnt_d,
                                               int* __restrict__ cnt_s,
                                               int* __restrict__ packed_d,
                                               unsigned char* __restrict__ packed_s8,
                                               const float* __restrict__ W1,
                                               const float* __restrict__ W2,
                                               _Float16* __restrict__ Wt1,
                                               _Float16* __restrict__ Wt2,
                                               const int* __restrict__ gid,
                                               int* __restrict__ gptr,
                                               int N, int E, int nbkt) {
  __shared__ int hd[512], hs[512], exd[512], exs[512], based[512], bases[512];
  __shared__ int sd[SCHUNK];
  __shared__ unsigned char ss[SCHUNK];
  const int t = threadIdx.x;
  const int bid = blockIdx.x;

  // prologue: Wt transpose spread over grid; gptr bsearch on last block
  for (int idx = bid * 512 + t; idx < 2 * 128 * 128; idx += gridDim.x * 512) {
    int m = idx >> 14, i = idx & 16383;
    int k = i >> 7, n = i & 127;
    (m ? Wt2 : Wt1)[n * 128 + k] = (_Float16)((m ? W2 : W1)[i]);
  }
  if (bid == gridDim.x - 1 && t <= 64) {  // gptr[g] = lower_bound(gid, g)
    int lo = 0, hi = N;
    while (lo < hi) {
      int m = (lo + hi) >> 1;
      if (gid[m] < t) lo = m + 1; else hi = m;
    }
    gptr[t] = lo;
  }

  hd[t] = 0; hs[t] = 0;
  __syncthreads();
  const int chunk = (E + gridDim.x - 1) / gridDim.x;  // == SCHUNK
  const int lo = bid * chunk, hi = min(lo + chunk, E);
  const int n = hi - lo;
  for (int i = lo + t; i < hi; i += 512) {
    atomicAdd(&hd[dst[i] >> BSH], 1);
    atomicAdd(&hs[src[i] >> BSH], 1);
  }
  __syncthreads();
  int cD = hd[t], cS = hs[t];
  // inclusive scans of both histograms (Hillis-Steele over 512)
  for (int off = 1; off < 512; off <<= 1) {
    int ad = (t >= off) ? hd[t - off] : 0;
    int as = (t >= off) ? hs[t - off] : 0;
    __syncthreads();
    hd[t] += ad; hs[t] += as;
    __syncthreads();
  }
  exd[t] = hd[t] - cD;
  exs[t] = hs[t] - cS;
  if (t < nbkt) {
    based[t] = cD ? atomicAdd(&cnt_d[t], cD) : 0;
    bases[t] = cS ? atomicAdd(&cnt_s[t], cS) : 0;
  }
  __syncthreads();
  hd[t] = 0; hs[t] = 0;   // reuse as rank counters
  __syncthreads();
  // rank-scatter into LDS (bucket-sorted order)
  for (int i = lo + t; i < hi; i += 512) {
    int s = src[i], d = dst[i];
    int b1 = d >> BSH;
    int r1 = atomicAdd(&hd[b1], 1);
    sd[exd[b1] + r1] = ((d & (BKT - 1)) << 17) | s;
    int b2 = s >> BSH;
    int r2 = atomicAdd(&hs[b2], 1);
    ss[exs[b2] + r2] = (unsigned char)(s & (BKT - 1));
  }
  __syncthreads();
  // linear flush: consecutive i in a bucket-run -> consecutive global addrs
  for (int i = t; i < n; i += 512) {
    int blo = 0, bhi = nbkt - 1;           // d-side: largest b, exd[b] <= i
    while (blo < bhi) {
      int m = (blo + bhi + 1) >> 1;
      if (exd[m] <= i) blo = m; else bhi = m - 1;
    }
    int p = based[blo] + (i - exd[blo]);
    if (p < CAP) packed_d[blo * CAP + p] = sd[i];
    blo = 0; bhi = nbkt - 1;               // s-side
    while (blo < bhi) {
      int m = (blo + bhi + 1) >> 1;
      if (exs[m] <= i) blo = m; else bhi = m - 1;
    }
    p = bases[blo] + (i - exs[blo]);
    if (p < CAP) packed_s8[blo * CAP + p] = ss[i];
  }
}

// ---------------- fine pass: blocks [0,nbkt) dst, [nbkt,2*nbkt) src ----------
// dst: per-bucket counting sort fully in LDS; csr written coalesced.
__global__ __launch_bounds__(512) void k_fine(const int* __restrict__ packed_d,
                                              const int* __restrict__ cnt_d,
                                              int* __restrict__ row_lo,
                                              int* __restrict__ row_hi,
                                              int* __restrict__ csr,
                                              const unsigned char* __restrict__ packed_s8,
                                              const int* __restrict__ cnt_s,
                                              float* __restrict__ norm_src,
                                              int N, int nbkt) {
  __shared__ int hist[256];
  int t = threadIdx.x;
  if (blockIdx.x >= nbkt) {
    // ---- src side: norm_src = rsqrt(max(deg_out,1)) ----
    int b = blockIdx.x - nbkt;
    size_t lo = (size_t)b * CAP;
    int cnt = min(cnt_s[b], CAP);
    if (t < 256) hist[t] = 0;
    __syncthreads();
    for (int e = t; e < cnt; e += 512)
      atomicAdd(&hist[packed_s8[lo + e]], 1);
    __syncthreads();
    int nbase = b << BSH;
    if (t < 256 && nbase + t < N)
      norm_src[nbase + t] = rsqrtf(fmaxf((float)hist[t], 1.0f));
    return;
  }
  // ---- dst side: row_lo/row_hi + csr ----
  __shared__ int excl[256];
  __shared__ int ecache[CAP];
  __shared__ int sorted[CAP];
  int b = blockIdx.x;
  int lo = b * CAP;
  int cnt = min(cnt_d[b], CAP);
  if (t < 256) hist[t] = 0;
  __syncthreads();
  for (int e = t; e < cnt; e += 512) {
    int p = packed_d[lo + e];
    ecache[e] = p;
    atomicAdd(&hist[p >> 17], 1);
  }
  __syncthreads();
  int v = (t < 256) ? hist[t] : 0;
  // inclusive scan of hist (256 entries; all threads hit barriers)
  for (int off = 1; off < 256; off <<= 1) {
    int a = (t >= off && t < 256) ? hist[t - off] : 0;
    __syncthreads();
    if (t < 256) hist[t] += a;
    __syncthreads();
  }
  int nbase = b << BSH;
  if (t < 256) {
    excl[t] = hist[t] - v;
    if (nbase + t < N) {
      row_lo[nbase + t] = lo + hist[t] - v;
      row_hi[nbase + t] = lo + hist[t];
    }
  }
  __syncthreads();
  if (t < 256) hist[t] = 0;  // reuse as rank counters
  __syncthreads();
  for (int e = t; e < cnt; e += 512) {
    int p = ecache[e];
    int dlow = p >> 17;
    int r = atomicAdd(&hist[dlow], 1);
    sorted[excl[dlow] + r] = p & 0x1FFFF;
  }
  __syncthreads();
  for (int e = t; e < cnt; e += 512)   // coalesced csr write
    csr[lo + e] = sorted[e];
}

// ---------------- MFMA GEMM (fp32 input): C(half) = (scale*A)@W ----------------
__global__ __launch_bounds__(256) void k_gemm1(const float* __restrict__ A,
                                               const _Float16* __restrict__ Wt,
                                               const float* __restrict__ scale,
                                               _Float16* __restrict__ C, int N) {
  __shared__ _Float16 As[64][136];
  __shared__ _Float16 Cs[64][128];
  const int r0 = blockIdx.x * 64;
  const int t = threadIdx.x;
  for (int i = t; i < 64 * 32; i += 256) {
    int r = i >> 5, c4 = i & 31;
    float4 v = {0.f, 0.f, 0.f, 0.f};
    if (r0 + r < N) {
      v = ((const float4*)A)[(size_t)(r0 + r) * 32 + c4];
      float s = scale[r0 + r];
      v.x *= s; v.y *= s; v.z *= s; v.w *= s;
    }
    half4v h = {(_Float16)v.x, (_Float16)v.y, (_Float16)v.z, (_Float16)v.w};
    *(half4v*)&As[r][c4 * 4] = h;
  }
  __syncthreads();
  const int w = t >> 6, l = t & 63;
  const int c = l & 15, quad = l >> 4;
  f32x4 acc[8];
#pragma unroll
  for (int nt = 0; nt < 8; ++nt) acc[nt] = (f32x4){0.f, 0.f, 0.f, 0.f};
#pragma unroll
  for (int kc = 0; kc < 4; ++kc) {
    half8 a = *(const half8*)&As[w * 16 + c][kc * 32 + quad * 8];
#pragma unroll
    for (int nt = 0; nt < 8; ++nt) {
      half8 b = *(const half8*)&Wt[(size_t)(nt * 16 + c) * 128 + kc * 32 + quad * 8];
      acc[nt] = __builtin_amdgcn_mfma_f32_16x16x32_f16(a, b, acc[nt], 0, 0, 0);
    }
  }
#pragma unroll
  for (int nt = 0; nt < 8; ++nt)
#pragma unroll
    for (int r = 0; r < 4; ++r)
      Cs[w * 16 + quad * 4 + r][nt * 16 + c] = (_Float16)acc[nt][r];
  __syncthreads();
  for (int i = t; i < 64 * 16; i += 256) {
    int r = i >> 4, c8 = i & 15;
    if (r0 + r < N)
      ((half8*)C)[(size_t)(r0 + r) * 16 + c8] = *(half8*)&Cs[r][c8 * 8];
  }
}

// ---------------- MFMA GEMM (fp16 pre-scaled input): C(half) = A@W -----------
__global__ __launch_bounds__(256) void k_gemm2(const _Float16* __restrict__ A,
                                               const _Float16* __restrict__ Wt,
                                               _Float16* __restrict__ C, int N) {
  __shared__ _Float16 As[64][136];
  __shared__ _Float16 Cs[64][128];
  const int r0 = blockIdx.x * 64;
  const int t = threadIdx.x;
  for (int i = t; i < 64 * 16; i += 256) {
    int r = i >> 4, c8 = i & 15;
    half8 v = {0, 0, 0, 0, 0, 0, 0, 0};
    if (r0 + r < N) v = ((const half8*)A)[(size_t)(r0 + r) * 16 + c8];
    *(half8*)&As[r][c8 * 8] = v;
  }
  __syncthreads();
  const int w = t >> 6, l = t & 63;
  const int c = l & 15, quad = l >> 4;
  f32x4 acc[8];
#pragma unroll
  for (int nt = 0; nt < 8; ++nt) acc[nt] = (f32x4){0.f, 0.f, 0.f, 0.f};
#pragma unroll
  for (int kc = 0; kc < 4; ++kc) {
    half8 a = *(const half8*)&As[w * 16 + c][kc * 32 + quad * 8];
#pragma unroll
    for (int nt = 0; nt < 8; ++nt) {
      half8 b = *(const half8*)&Wt[(size_t)(nt * 16 + c) * 128 + kc * 32 + quad * 8];
      acc[nt] = __builtin_amdgcn_mfma_f32_16x16x32_f16(a, b, acc[nt], 0, 0, 0);
    }
  }
#pragma unroll
  for (int nt = 0; nt < 8; ++nt)
#pragma unroll
    for (int r = 0; r < 4; ++r)
      Cs[w * 16 + quad * 4 + r][nt * 16 + c] = (_Float16)acc[nt][r];
  __syncthreads();
  for (int i = t; i < 64 * 16; i += 256) {
    int r = i >> 4, c8 = i & 15;
    if (r0 + r < N)
      ((half8*)C)[(size_t)(r0 + r) * 16 + c8] = *(half8*)&Cs[r][c8 * 8];
  }
}

// ---------------- gather core ----------------
#define PK_ROW(u)                                                           \
  _Pragma("unroll")                                                         \
  for (int k = 0; k < 4; ++k) acch[k] += (u).h[k];

__device__ __forceinline__ void gather_core(const half8* __restrict__ P8,
                                            const int* __restrict__ csr,
                                            int start, int end, int cg, int eg,
                                            int lane, float* acc) {
  half2v acch[4] = {{(_Float16)0.f, (_Float16)0.f}, {(_Float16)0.f, (_Float16)0.f},
                    {(_Float16)0.f, (_Float16)0.f}, {(_Float16)0.f, (_Float16)0.f}};
  for (int s0 = start; s0 < end; s0 += 64) {
    int cnt = min(64, end - s0);
    int idx = (s0 + lane < end) ? csr[s0 + lane] : 0;
    int base = 0;
    for (; base + 16 <= cnt; base += 16) {
      int i0 = __shfl(idx, base + eg);
      int i1 = __shfl(idx, base + 4 + eg);
      int i2 = __shfl(idx, base + 8 + eg);
      int i3 = __shfl(idx, base + 12 + eg);
      H8 u0, u1, u2, u3;
      u0.v = P8[(size_t)i0 * 16 + cg];
      u1.v = P8[(size_t)i1 * 16 + cg];
      u2.v = P8[(size_t)i2 * 16 + cg];
      u3.v = P8[(size_t)i3 * 16 + cg];
      PK_ROW(u0) PK_ROW(u1) PK_ROW(u2) PK_ROW(u3)
    }
    for (; base + 4 <= cnt; base += 4) {
      int i0 = __shfl(idx, base + eg);
      H8 u0;
      u0.v = P8[(size_t)i0 * 16 + cg];
      PK_ROW(u0)
    }
    if (base < cnt) {  // 1-3 tail edges
      int j = min(base + eg, cnt - 1);
      int i0 = __shfl(idx, j);
      if (base + eg < cnt) {
        H8 u0;
        u0.v = P8[(size_t)i0 * 16 + cg];
        PK_ROW(u0)
      }
    }
  }
#pragma unroll
  for (int k = 0; k < 4; ++k) {
    acc[2 * k]     = (float)acch[k].x;
    acc[2 * k + 1] = (float)acch[k].y;
  }
#pragma unroll
  for (int j = 0; j < 8; ++j) {
    acc[j] += __shfl_xor(acc[j], 16);
    acc[j] += __shfl_xor(acc[j], 32);
  }
}

// gather 1: h1' = norm_src * relu(agg*nd + b), fp16 out
__global__ __launch_bounds__(256) void k_gather1(const half8* __restrict__ P8,
                                                 const int* __restrict__ row_lo,
                                                 const int* __restrict__ row_hi,
                                                 const int* __restrict__ csr,
                                                 const float* __restrict__ bias,
                                                 const float* __restrict__ norm_src,
                                                 half2v* __restrict__ outH, int N) {
  int wid = (blockIdx.x * 256 + threadIdx.x) >> 6;
  if (wid >= N) return;
  int lane = threadIdx.x & 63;
  int cg = lane & 15, eg = lane >> 4;
  int start = row_lo[wid], end = row_hi[wid];
  float acc[8];
  gather_core(P8, csr, start, end, cg, eg, lane, acc);
  float nd = rsqrtf(fmaxf((float)(end - start), 1.0f));
  float ns = norm_src[wid];
  float2 b = ((const float2*)bias)[cg * 4 + eg];
  half2v o = {(_Float16)(fmaxf(acc[eg * 2] * nd + b.x, 0.f) * ns),
              (_Float16)(fmaxf(acc[eg * 2 + 1] * nd + b.y, 0.f) * ns)};
  outH[(size_t)wid * 64 + cg * 4 + eg] = o;
}

// gather 2: h2 = relu(agg*nd + b), fp32 out
__global__ __launch_bounds__(256) void k_gather2(const half8* __restrict__ P8,
                                                 const int* __restrict__ row_lo,
                                                 const int* __restrict__ row_hi,
                                                 const int* __restrict__ csr,
                                                 const float* __restrict__ bias,
                                                 float2* __restrict__ outH, int N) {
  int wid = (blockIdx.x * 256 + threadIdx.x) >> 6;
  if (wid >= N) return;
  int lane = threadIdx.x & 63;
  int cg = lane & 15, eg = lane >> 4;
  int start = row_lo[wid], end = row_hi[wid];
  float acc[8];
  gather_core(P8, csr, start, end, cg, eg, lane, acc);
  float nd = rsqrtf(fmaxf((float)(end - start), 1.0f));
  float2 b = ((const float2*)bias)[cg * 4 + eg];
  float2 o;
  o.x = fmaxf(acc[eg * 2] * nd + b.x, 0.f);
  o.y = fmaxf(acc[eg * 2 + 1] * nd + b.y, 0.f);
  outH[(size_t)wid * 64 + cg * 4 + eg] = o;
}

// ---------------- segment-sum pooling over sorted graph_id ----------------
__global__ __launch_bounds__(256) void k_pool(const float* __restrict__ H,
                                              const int* __restrict__ gptr,
                                              float* __restrict__ pool) {
  int g = blockIdx.x >> 3, chunk = blockIdx.x & 7;
  int col = threadIdx.x & 127, rpar = threadIdx.x >> 7;
  int s = gptr[g], e = gptr[g + 1];
  float acc = 0.0f;
  for (int r = s + chunk * 2 + rpar; r < e; r += 16)
    acc += H[(size_t)r * D + col];
  __shared__ float red[256];
  red[threadIdx.x] = acc;
  __syncthreads();
  if (rpar == 0) atomicAdd(&pool[g * D + col], acc + red[threadIdx.x + 128]);
}

// ---------------- readout MLP ----------------
__global__ __launch_bounds__(128) void k_readout(const float* __restrict__ pool,
                                                 const int* __restrict__ gptr,
                                                 const float* __restrict__ Wr1,
                                                 const float* __restrict__ br1,
                                                 const float* __restrict__ Wr2,
                                                 const float* __restrict__ br2,
                                                 float* __restrict__ out) {
  int g = blockIdx.x;
  int j = threadIdx.x;
  __shared__ float hg[D];
  __shared__ float t1[D];
  float cnt = fmaxf((float)(gptr[g + 1] - gptr[g]), 1.0f);
  hg[j] = pool[(size_t)g * D + j] / cnt;
  __syncthreads();
  float a = br1[j];
  for (int k = 0; k < D; ++k) a += hg[k] * Wr1[(size_t)k * D + j];
  t1[j] = fmaxf(a, 0.0f);
  __syncthreads();
  float b = br2[j];
  for (int k = 0; k < D; ++k) b += t1[k] * Wr2[(size_t)k * D + j];
  out[(size_t)g * D + j] = b;
}

extern "C" void kernel_launch(void* const* d_in, const int* in_sizes, int n_in,
                              void* d_out, int out_size, void* d_ws, size_t ws_size,
                              hipStream_t stream) {
  const float* x   = (const float*)d_in[0];
  const int* edge  = (const int*)d_in[1];
  const int* gid   = (const int*)d_in[2];
  const float* W1  = (const float*)d_in[4];
  const float* b1  = (const float*)d_in[5];
  const float* W2  = (const float*)d_in[6];
  const float* b2  = (const float*)d_in[7];
  const float* Wr1 = (const float*)d_in[8];
  const float* br1 = (const float*)d_in[9];
  const float* Wr2 = (const float*)d_in[10];
  const float* br2 = (const float*)d_in[11];

  const int N = in_sizes[0] / D;   // 100000
  const int E = in_sizes[1] / 2;   // 1600000
  const int* src = edge;
  const int* dst = edge + E;
  const int nbkt = (N + BKT - 1) >> BSH;  // 391

  // workspace layout
  float* bufA     = (float*)d_ws;                    // P (half N*128) lives here
  float* bufB     = bufA + (size_t)N * D;            // h1' (half N*128) lives here
  int* row_lo     = (int*)(bufB + (size_t)N * D);    // N
  int* row_hi     = row_lo + N;                      // N
  int* csr        = row_hi + N;                      // nbkt*CAP (bucket-padded)
  float* norm_src = (float*)(csr + (size_t)nbkt * CAP);  // N
  float* pool     = norm_src + N;                    // 64*128
  int* gptr       = (int*)(pool + 64 * D);           // 65
  int* cnt_d      = gptr + 65;                       // 512
  int* cnt_s      = cnt_d + 512;                     // 512 (adjacent)
  _Float16* Wt1   = (_Float16*)(cnt_s + 512);        // 128*128 halves
  _Float16* Wt2   = Wt1 + 128 * 128;                 // 128*128 halves
  // temporaries aliasing bufA (consumed by k_fine before gemm1 writes P)
  int* packed_d   = (int*)bufA;                      // nbkt*CAP ints
  unsigned char* packed_s8 = (unsigned char*)(packed_d + (size_t)nbkt * CAP);
  size_t need = ((size_t)2 * N * D + 3 * (size_t)N + (size_t)nbkt * CAP
                 + 64 * D + 65 + 1024 + 16384 + 1024) * sizeof(float);
  if (ws_size < need) return;

  float* out_g = (float*)d_out;      // 64*128
  float* h_out = out_g + 64 * D;     // N*128

  _Float16* P   = (_Float16*)bufA;
  _Float16* h1p = (_Float16*)bufB;

  // single memset span: pool (8192) | gptr (65) | cnt_d+cnt_s (1024)
  hipMemsetAsync(pool, 0, (64 * D + 65 + 1024) * sizeof(float), stream);

  // build: prologue + histogram + scan + reserve + LDS sort + coalesced flush
  const int build_grid = (E + SCHUNK - 1) / SCHUNK;  // 500
  k_build<<<build_grid, 512, 0, stream>>>(src, dst, cnt_d, cnt_s,
                                          packed_d, packed_s8,
                                          W1, W2, Wt1, Wt2, gid, gptr,
                                          N, E, nbkt);
  k_fine<<<2 * nbkt, 512, 0, stream>>>(packed_d, cnt_d, row_lo, row_hi, csr,
                                       packed_s8, cnt_s, norm_src, N, nbkt);

  const int gemm_grid = (N + 63) / 64;

  // layer 1
  k_gemm1<<<gemm_grid, 256, 0, stream>>>(x, Wt1, norm_src, P, N);
  k_gather1<<<(N * 64 + 255) / 256, 256, 0, stream>>>(
      (const half8*)P, row_lo, row_hi, csr, b1, norm_src, (half2v*)h1p, N);

  // layer 2
  k_gemm2<<<gemm_grid, 256, 0, stream>>>(h1p, Wt2, P, N);
  k_gather2<<<(N * 64 + 255) / 256, 256, 0, stream>>>(
      (const half8*)P, row_lo, row_hi, csr, b2, (float2*)h_out, N);

  // pooling + readout
  k_pool<<<64 * 8, 256, 0, stream>>>(h_out, gptr, pool);
  k_readout<<<64, 128, 0, stream>>>(pool, gptr, Wr1, br1, Wr2, br2, out_g);
}